// Round 8
// baseline (244.749 us; speedup 1.0000x reference)
//
#include <hip/hip_runtime.h>
#include <hip/hip_bf16.h>

#define NN 1024
#define DH 64
#define DIM 512
#define INNER 512
#define QKV_N 1536
#define QPRESCALE 0.1803368801111244f   // 0.125 * log2(e): softmax exp via exp2
#define PPITCH 72     // shorts; Ps plane (144B = 9*16B: b128-aligned)

typedef short short8 __attribute__((ext_vector_type(8)));
typedef float floatx4 __attribute__((ext_vector_type(4)));

static __device__ __forceinline__ unsigned short f2bf(float x) {
  __hip_bfloat16 h = __float2bfloat16(x);
  unsigned short u;
  __builtin_memcpy(&u, &h, 2);
  return u;
}
static __device__ __forceinline__ void splitbf(float x, unsigned short& hi, unsigned short& lo) {
  __hip_bfloat16 h = __float2bfloat16(x);
  float hf = __bfloat162float(h);
  __hip_bfloat16 l = __float2bfloat16(x - hf);
  __builtin_memcpy(&hi, &h, 2);
  __builtin_memcpy(&lo, &l, 2);
}
static __device__ __forceinline__ void gll16(const unsigned short* g, unsigned short* l) {
  __builtin_amdgcn_global_load_lds(
      (const __attribute__((address_space(1))) unsigned int*)g,
      (__attribute__((address_space(3))) unsigned int*)l, 16, 0, 0);
}

// ---------------- fused prep: split x | transpose+split weights | nnz+mask bits ----------------
__global__ __launch_bounds__(256) void prep_kernel(const float* __restrict__ x,
                                                   const float* __restrict__ w_qkv,
                                                   const float* __restrict__ w_out,
                                                   const int* __restrict__ mask,
                                                   unsigned short* __restrict__ xhi,
                                                   unsigned short* __restrict__ xlo,
                                                   unsigned short* __restrict__ wqhiT,
                                                   unsigned short* __restrict__ wqloT,
                                                   unsigned short* __restrict__ wohiT,
                                                   unsigned short* __restrict__ woloT,
                                                   float* __restrict__ nnzf,
                                                   unsigned long long* __restrict__ Mbits) {
  __shared__ float tile[32][33];
  int blk = blockIdx.x;
  int t = threadIdx.x;
  if (blk < 4096) {
    // split x (fp32 -> hi/lo bf16), float4 granularity
    int i = blk * 256 + t;
    float4 v = ((const float4*)x)[i];
    ushort4 h, l;
    splitbf(v.x, h.x, l.x);
    splitbf(v.y, h.y, l.y);
    splitbf(v.z, h.z, l.z);
    splitbf(v.w, h.w, l.w);
    ((ushort4*)xhi)[i] = h;
    ((ushort4*)xlo)[i] = l;
  } else if (blk < 5120) {
    // transpose + split a weight tile
    const float* in;
    unsigned short *hiT, *loT;
    int K = 512, N, n0, k0;
    if (blk < 4864) {
      int idx = blk - 4096;
      in = w_qkv; hiT = wqhiT; loT = wqloT; N = QKV_N;
      n0 = (idx % 48) * 32; k0 = (idx / 48) * 32;
    } else {
      int idx = blk - 4864;
      in = w_out; hiT = wohiT; loT = woloT; N = DIM;
      n0 = (idx % 16) * 32; k0 = (idx / 16) * 32;
    }
    int tn = t & 31, tk = t >> 5;
#pragma unroll
    for (int i = 0; i < 32; i += 8)
      tile[tk + i][tn] = in[(size_t)(k0 + tk + i) * N + n0 + tn];
    __syncthreads();
#pragma unroll
    for (int i = 0; i < 32; i += 8) {
      int n = tk + i;
      float v = tile[tn][n];
      unsigned short h, l;
      splitbf(v, h, l);
      hiT[(size_t)(n0 + n) * K + k0 + tn] = h;
      loT[(size_t)(n0 + n) * K + k0 + tn] = l;
    }
  } else {
    // nnz + mask bits: one wave per mask row (Mbits layout [mt][row])
    int row = (blk - 5120) * 4 + (t >> 6);
    int lane = t & 63;
    const int* mrow = mask + (size_t)row * NN;
    int tot = 0;
    for (int mt = 0; mt < 16; ++mt) {
      unsigned long long bits = __ballot(mrow[mt * 64 + lane] != 0);
      if (lane == 0) {
        Mbits[(size_t)mt * NN + row] = bits;
        tot += __popcll(bits);
      }
    }
    if (lane == 0) nnzf[row] = (float)tot;
  }
}

// ---------------- QKV GEMM: B staged via swizzled gll16, A direct-global, 33.8 KB LDS ----------------
// grid 768 1-D: by = l&63 (row tile), bx = l>>6 (col tile). Same-A blocks share XCD (%8).
__global__ __launch_bounds__(256) void qkv_mfma(const unsigned short* __restrict__ xhi,
                                                const unsigned short* __restrict__ xlo,
                                                const unsigned short* __restrict__ bhiT,
                                                const unsigned short* __restrict__ bloT,
                                                unsigned short* __restrict__ qhi,
                                                unsigned short* __restrict__ qlo,
                                                unsigned short* __restrict__ khi,
                                                unsigned short* __restrict__ klo,
                                                unsigned short* __restrict__ vT) {
  // union: B planes [128][64]x2 (32768 B) | epilogue fp32 half-tile [64][132] (33792 B)
  __shared__ __align__(16) unsigned char smemQ[33792];
  unsigned short* Bh = (unsigned short*)smemQ;
  unsigned short* Bl = Bh + 8192;
  float* ct = (float*)smemQ;

  int l = blockIdx.x;
  int by = l & 63, bx = l >> 6;
  int r0 = by * 128, c0 = bx * 128;
  int which = c0 >> 9;                 // 0=q, 1=k, 2=v
  bool split3 = (which != 2);          // v: hi*hi only (rounded to bf16 anyway)
  int t = threadIdx.x;
  int lane = t & 63, w = t >> 6;
  int wr = w >> 1, wc = w & 1;
  int s = lane & 15, q4 = lane >> 4;
  int sx7 = s & 7;
  int r8 = lane >> 3, j7 = lane & 7;
  int colsw = ((j7 ^ r8) << 3);        // full-line swizzle keyed to (lds_row & 7)

  // A direct-global per-lane fragment base
  const unsigned short* aHb = xhi + (size_t)(r0 + wr * 64 + s) * DIM + q4 * 8;
  const unsigned short* aLb = xlo + (size_t)(r0 + wr * 64 + s) * DIM + q4 * 8;
  // B staging source (wave w stages rows 32w..32w+31 of each plane)
  const unsigned short* gBh = bhiT + (size_t)(c0 + 32 * w + r8) * DIM + colsw;
  const unsigned short* gBl = bloT + (size_t)(c0 + 32 * w + r8) * DIM + colsw;

  floatx4 acc[4][4];
#pragma unroll
  for (int mi = 0; mi < 4; ++mi)
#pragma unroll
    for (int ni = 0; ni < 4; ++ni) { acc[mi][ni][0] = 0.f; acc[mi][ni][1] = 0.f; acc[mi][ni][2] = 0.f; acc[mi][ni][3] = 0.f; }

  for (int kt = 0; kt < DIM; kt += 64) {
    __syncthreads();
#pragma unroll
    for (int ii = 0; ii < 4; ++ii) {
      int lofs = (32 * w + 8 * ii) * 64;
      gll16(gBh + (size_t)ii * 8 * DIM + kt, Bh + lofs);
      if (split3) gll16(gBl + (size_t)ii * 8 * DIM + kt, Bl + lofs);
    }
    __syncthreads();
#pragma unroll
    for (int ks2 = 0; ks2 < 2; ++ks2) {
      int pc = ((ks2 * 4 + q4) ^ sx7) << 3;
      int ko = kt + ks2 * 32;
      short8 ah[4], al[4], bhf[4], blf[4];
#pragma unroll
      for (int mi = 0; mi < 4; ++mi) {
        ah[mi] = *(const short8*)(aHb + (size_t)mi * 16 * DIM + ko);
        if (split3) al[mi] = *(const short8*)(aLb + (size_t)mi * 16 * DIM + ko);
      }
#pragma unroll
      for (int ni = 0; ni < 4; ++ni) {
        int rb = (wc * 64 + ni * 16 + s) * 64 + pc;
        bhf[ni] = *(const short8*)&Bh[rb];
        if (split3) blf[ni] = *(const short8*)&Bl[rb];
      }
#pragma unroll
      for (int mi = 0; mi < 4; ++mi)
#pragma unroll
        for (int ni = 0; ni < 4; ++ni) {
          if (split3) {
            acc[mi][ni] = __builtin_amdgcn_mfma_f32_16x16x32_bf16(al[mi], bhf[ni], acc[mi][ni], 0, 0, 0);
            acc[mi][ni] = __builtin_amdgcn_mfma_f32_16x16x32_bf16(ah[mi], blf[ni], acc[mi][ni], 0, 0, 0);
          }
          acc[mi][ni] = __builtin_amdgcn_mfma_f32_16x16x32_bf16(ah[mi], bhf[ni], acc[mi][ni], 0, 0, 0);
        }
    }
  }

  // ---- epilogue: two half-tile fp32 LDS relayout passes -> full-line stores ----
  int b = r0 >> 10;
  __syncthreads();   // ct aliases B staging planes
  if (which != 2) {
    float scf = (which == 0) ? QPRESCALE : 1.0f;   // q pre-scaled by 0.125*log2e
    unsigned short* dhi = (which == 0) ? qhi : khi;
    unsigned short* dlo = (which == 0) ? qlo : klo;
    int hb = (c0 & 511) >> 6;
#pragma unroll
    for (int p = 0; p < 2; ++p) {
      if (p) __syncthreads();
      if (wr == p) {
#pragma unroll
        for (int mi = 0; mi < 4; ++mi)
#pragma unroll
          for (int ni = 0; ni < 4; ++ni)
#pragma unroll
            for (int i = 0; i < 4; ++i)
              ct[(mi * 16 + q4 * 4 + i) * 132 + (wc * 64 + ni * 16 + s)] = acc[mi][ni][i] * scf;
      }
      __syncthreads();
      {
        int tr = t >> 2, seg = t & 3;
        int h = hb + (seg >> 1);
        int d0 = (seg & 1) * 32;
        int n = (r0 & 1023) + 64 * p + tr;
        size_t go = ((size_t)(((b << 3) + h) << 10) + n) * DH + d0;
        const float* src = &ct[tr * 132 + seg * 32];
        short8 h8[4], l8[4];
#pragma unroll
        for (int u = 0; u < 4; ++u)
#pragma unroll
          for (int e = 0; e < 8; ++e) {
            unsigned short hh, ll;
            splitbf(src[u * 8 + e], hh, ll);
            h8[u][e] = (short)hh; l8[u][e] = (short)ll;
          }
#pragma unroll
        for (int u = 0; u < 4; ++u) {
          *(short8*)&dhi[go + u * 8] = h8[u];
          *(short8*)&dlo[go + u * 8] = l8[u];
        }
      }
    }
  } else {
    int hb = (c0 & 511) >> 6;
#pragma unroll
    for (int p = 0; p < 2; ++p) {
      if (p) __syncthreads();
      if (wc == p) {
#pragma unroll
        for (int mi = 0; mi < 4; ++mi)
#pragma unroll
          for (int ni = 0; ni < 4; ++ni)
#pragma unroll
            for (int i = 0; i < 4; ++i)
              ct[(ni * 16 + s) * 132 + (wr * 64 + mi * 16 + q4 * 4 + i)] = acc[mi][ni][i];
      }
      __syncthreads();
      {
        int d = t >> 2, nseg = t & 3;
        int h = hb + p;
        int n0 = (r0 & 1023) + nseg * 32;
        size_t go = ((size_t)(((b << 3) + h) * DH) + d) * NN + n0;
        const float* src = &ct[d * 132 + nseg * 32];
        short8 o[4];
#pragma unroll
        for (int u = 0; u < 4; ++u)
#pragma unroll
          for (int e = 0; e < 8; ++e) o[u][e] = (short)f2bf(src[u * 8 + e]);
#pragma unroll
        for (int u = 0; u < 4; ++u) *(short8*)&vT[go + u * 8] = o[u];
      }
    }
  }
}

// ---------------- MFMA flash attention: R5 structure + exp2/cndmask softmax ----------------
__global__ __launch_bounds__(256, 4) void attn_kernel(const unsigned short* __restrict__ qhi,
                                                      const unsigned short* __restrict__ qlo,
                                                      const unsigned short* __restrict__ khi,
                                                      const unsigned short* __restrict__ klo,
                                                      const unsigned short* __restrict__ vT,
                                                      const unsigned long long* __restrict__ MbT,
                                                      unsigned short* __restrict__ ohi,
                                                      unsigned short* __restrict__ olo,
                                                      float* __restrict__ sph) {
  // XCD-affine swizzle: all 16 rb-blocks of one bh share (linear % 8)
  int l = blockIdx.y * 16 + blockIdx.x;
  int k = l >> 3;
  int rb = k & 15;
  int bh = (l & 7) + 8 * (k >> 4);
  int b = bh >> 3, h = bh & 7;
  int row0 = rb * 64;
  int t = threadIdx.x;
  int lane = t & 63, w = t >> 6;
  int q4 = lane >> 4, s = lane & 15;
  int sx7 = s & 7;
  int gr = 16 * w + s;
  int r8 = lane >> 3, j7 = lane & 7;
  int colsw = ((j7 ^ r8) << 3);

  __shared__ __align__(16) unsigned short stageS[3 * 4096];  // Khs | Kls | Vts, [64][64] each
  __shared__ __align__(16) unsigned short Ps[64 * PPITCH];
  __shared__ unsigned long long Mb[64];
  unsigned short* Khs = stageS;
  unsigned short* Kls = stageS + 4096;
  unsigned short* Vts = stageS + 8192;
  float* Ofl = (float*)stageS;   // [64][68] fp32, reused after main loop

  const unsigned short* khp = khi + ((size_t)bh * NN + 16 * w + r8) * DH + colsw;
  const unsigned short* klp = klo + ((size_t)bh * NN + 16 * w + r8) * DH + colsw;
  const unsigned short* vtp = vT + ((size_t)bh * DH + 16 * w + r8) * NN + colsw;

  // Q fragments: direct global->register (pre-scaled by 0.125*log2e, pre-split)
  short8 aqh[2], aql[2];
  {
    size_t qb0 = ((size_t)bh * NN + row0 + gr) * DH;
#pragma unroll
    for (int ks = 0; ks < 2; ++ks) {
      aqh[ks] = *(const short8*)&qhi[qb0 + ks * 32 + q4 * 8];
      aql[ks] = *(const short8*)&qlo[qb0 + ks * 32 + q4 * 8];
    }
  }

  floatx4 Oacc[4];
  float Lacc[4], Sco[4];
#pragma unroll
  for (int j = 0; j < 4; ++j) { Oacc[j][0] = 0.f; Oacc[j][1] = 0.f; Oacc[j][2] = 0.f; Oacc[j][3] = 0.f; }
#pragma unroll
  for (int i = 0; i < 4; ++i) { Lacc[i] = 0.f; Sco[i] = 0.f; }

  for (int mt = 0; mt < 16; ++mt) {
    __syncthreads();
#pragma unroll
    for (int ii = 0; ii < 2; ++ii) {
      int lofs = (16 * w + 8 * ii) * 64;
      gll16(khp + (size_t)mt * 64 * DH + (size_t)ii * 8 * DH, Khs + lofs);
      gll16(klp + (size_t)mt * 64 * DH + (size_t)ii * 8 * DH, Kls + lofs);
      gll16(vtp + (size_t)mt * 64 + (size_t)ii * 8 * NN, Vts + lofs);
    }
    if (t < 64) Mb[t] = MbT[(size_t)mt * NN + row0 + t];
    __syncthreads();

    // ---- S = Q K^T (3-MFMA split; logits pre-scaled incl. log2e) ----
    floatx4 Sf[4];
#pragma unroll
    for (int j = 0; j < 4; ++j) { Sf[j][0] = 0.f; Sf[j][1] = 0.f; Sf[j][2] = 0.f; Sf[j][3] = 0.f; }
#pragma unroll
    for (int ks = 0; ks < 2; ++ks) {
      int pc = ((ks * 4 + q4) ^ sx7) << 3;
#pragma unroll
      for (int j = 0; j < 4; ++j) {
        int rk = (16 * j + s) * 64 + pc;
        short8 kh8 = *(const short8*)&Khs[rk];
        short8 kl8 = *(const short8*)&Kls[rk];
        Sf[j] = __builtin_amdgcn_mfma_f32_16x16x32_bf16(aql[ks], kh8, Sf[j], 0, 0, 0);
        Sf[j] = __builtin_amdgcn_mfma_f32_16x16x32_bf16(aqh[ks], kl8, Sf[j], 0, 0, 0);
        Sf[j] = __builtin_amdgcn_mfma_f32_16x16x32_bf16(aqh[ks], kh8, Sf[j], 0, 0, 0);
      }
    }

    // ---- softmax via exp2 on masked logits (cndmask; exp2(0)=1 == masked ref) ----
    unsigned short pw[4][4];
#pragma unroll
    for (int i = 0; i < 4; ++i) {
      unsigned long long u = Mb[16 * w + 4 * q4 + i] >> s;   // bits for j at 16j
#pragma unroll
      for (int j = 0; j < 4; ++j) {
        float sv = Sf[j][i];
        float tv = ((u >> (16 * j)) & 1ULL) ? sv : 0.0f;
        Sco[i] += fabsf(tv);           // uniform-scaled |dot|: order-exact for argsort
        float p = exp2f(tv);
        Lacc[i] += p;
        pw[i][j] = f2bf(p);
      }
    }

    // ---- P: C-layout -> A-layout via intra-wave LDS round-trip (no barrier) ----
#pragma unroll
    for (int i = 0; i < 4; ++i)
#pragma unroll
      for (int j = 0; j < 4; ++j) Ps[(16 * w + 4 * q4 + i) * PPITCH + 16 * j + s] = pw[i][j];

    // ---- O += P V ----
#pragma unroll
    for (int ks = 0; ks < 2; ++ks) {
      short8 ap = *(const short8*)&Ps[gr * PPITCH + ks * 32 + q4 * 8];
      int pc = ((ks * 4 + q4) ^ sx7) << 3;
#pragma unroll
      for (int j = 0; j < 4; ++j) {
        short8 bv = *(const short8*)&Vts[(16 * j + s) * 64 + pc];
        Oacc[j] = __builtin_amdgcn_mfma_f32_16x16x32_bf16(ap, bv, Oacc[j], 0, 0, 0);
      }
    }
  }

  // ---- final cross-lane reduction, sph ----
#pragma unroll
  for (int off = 1; off < 16; off <<= 1) {
#pragma unroll
    for (int i = 0; i < 4; ++i) {
      Lacc[i] += __shfl_xor(Lacc[i], off, 16);
      Sco[i] += __shfl_xor(Sco[i], off, 16);
    }
  }
  if (s == 0) {
#pragma unroll
    for (int i = 0; i < 4; ++i)
      sph[((size_t)bh << 10) + row0 + 16 * w + 4 * q4 + i] = Sco[i];
  }

  // ---- O epilogue: fp32 LDS relayout -> full-line split-bf16 stores ----
  __syncthreads();   // Ofl aliases staging
#pragma unroll
  for (int i = 0; i < 4; ++i) {
    float iv = 1.0f / Lacc[i];
#pragma unroll
    for (int j = 0; j < 4; ++j)
      Ofl[(16 * w + 4 * q4 + i) * 68 + 16 * j + s] = Oacc[j][i] * iv;
  }
  __syncthreads();
  {
    int tr = t >> 2, dq = t & 3;
    int r = row0 + tr;
    size_t go = ((size_t)((b << 10) + r)) * INNER + (h << 6) + dq * 16;
    const float* src = &Ofl[tr * 68 + dq * 16];
    short8 h8a, h8b, l8a, l8b;
#pragma unroll
    for (int e = 0; e < 8; ++e) {
      unsigned short hh, ll;
      splitbf(src[e], hh, ll);
      h8a[e] = (short)hh; l8a[e] = (short)ll;
      splitbf(src[8 + e], hh, ll);
      h8b[e] = (short)hh; l8b[e] = (short)ll;
    }
    *(short8*)&ohi[go] = h8a;
    *(short8*)&ohi[go + 8] = h8b;
    *(short8*)&olo[go] = l8a;
    *(short8*)&olo[go + 8] = l8b;
  }
}

// ---------------- fused score+select+build: block bi selects batch bi, builds src for batch 7-bi ----------------
__global__ __launch_bounds__(64) void sel_build(const float* __restrict__ sph,
                                                const float* __restrict__ nnzf,
                                                const int* __restrict__ pic_ptr,
                                                int* __restrict__ src) {
  int bb = blockIdx.x;
  int lane = threadIdx.x;
  int pic = pic_ptr[0];
  int cnt = pic + 1;
  int ob = 7 - bb;   // idx = argsort(score)[::-1] reverses BATCH axis: src[ob] consumes asc of bb
  float v[16];
#pragma unroll
  for (int i = 0; i < 16; ++i) {
    int r = i * 64 + lane;
    float sv = 0.f;
#pragma unroll
    for (int h = 0; h < 8; ++h) sv += sph[(size_t)(((bb << 3) + h) << 10) + r];
    v[i] = sv / nnzf[r];   // uniform positive scale vs ref: ordering identical
  }
  // init gather map (wave-lockstep: completes before the swap writes below)
#pragma unroll
  for (int i = 0; i < 16; ++i) src[ob * 1024 + i * 64 + lane] = i * 64 + lane;
  for (int sel = 0; sel < cnt; ++sel) {
    float bv = v[0];
    int bi = lane;
#pragma unroll
    for (int i = 1; i < 16; ++i) {
      int r = i * 64 + lane;
      if (v[i] < bv) { bv = v[i]; bi = r; }   // ascending i -> smallest index on ties
    }
#pragma unroll
    for (int off = 1; off < 64; off <<= 1) {
      float ov = __shfl_xor(bv, off, 64);
      int oi = __shfl_xor(bi, off, 64);
      if (ov < bv || (ov == bv && oi < bi)) { bv = ov; bi = oi; }
    }
    // all lanes now agree on (bv, bi)
    if ((bi & 63) == lane) {
      int slot = bi >> 6;
#pragma unroll
      for (int i = 0; i < 16; ++i)
        if (i == slot) v[i] = 3.4e38f;
    }
    if (sel >= 1 && lane == 0) {
      src[ob * 1024 + sel] = bi;
      src[ob * 1024 + bi] = sel;
    }
  }
}

// ---------------- out GEMM: A (gathered) staged via gll16, B direct-global, 32 KB LDS ----------------
// grid 256 1-D: by = l&63 (row tile), bx = l>>6 (col tile)
__global__ __launch_bounds__(256) void out_mfma(const unsigned short* __restrict__ ahi,
                                                const unsigned short* __restrict__ alo,
                                                const unsigned short* __restrict__ bhiT,
                                                const unsigned short* __restrict__ bloT,
                                                const float* __restrict__ bias,
                                                const int* __restrict__ src,
                                                float* __restrict__ C) {
  __shared__ __align__(16) unsigned short planeS[2 * 8192];  // Ah | Al, [128][64] each
  int l = blockIdx.x;
  int by = l & 63, bx = l >> 6;
  int r0 = by * 128, c0 = bx * 128;
  int t = threadIdx.x;
  int lane = t & 63, w = t >> 6;
  int wr = w >> 1, wc = w & 1;
  int s = lane & 15, q4 = lane >> 4;
  int sx7 = s & 7;
  int r8 = lane >> 3, j7 = lane & 7;
  int colsw = ((j7 ^ r8) << 3);
  int bb1024 = (r0 >> 10) << 10;

  unsigned short* Ah = planeS;
  unsigned short* Al = planeS + 8192;

  // gathered A rows for this wave's staging slots (wave w stages rows 32w..32w+31)
  int grow[4];
#pragma unroll
  for (int ii = 0; ii < 4; ++ii)
    grow[ii] = bb1024 + src[r0 + 32 * w + 8 * ii + r8];

  const unsigned short* bHb = bhiT + (size_t)(c0 + wc * 64 + s) * INNER + q4 * 8;
  const unsigned short* bLb = bloT + (size_t)(c0 + wc * 64 + s) * INNER + q4 * 8;

  floatx4 acc[4][4];
#pragma unroll
  for (int mi = 0; mi < 4; ++mi)
#pragma unroll
    for (int ni = 0; ni < 4; ++ni) { acc[mi][ni][0] = 0.f; acc[mi][ni][1] = 0.f; acc[mi][ni][2] = 0.f; acc[mi][ni][3] = 0.f; }

  for (int kt = 0; kt < INNER; kt += 64) {
    __syncthreads();
#pragma unroll
    for (int ii = 0; ii < 4; ++ii) {
      int lofs = (32 * w + 8 * ii) * 64;
      gll16(ahi + (size_t)grow[ii] * INNER + kt + colsw, Ah + lofs);
      gll16(alo + (size_t)grow[ii] * INNER + kt + colsw, Al + lofs);
    }
    __syncthreads();
#pragma unroll
    for (int ks2 = 0; ks2 < 2; ++ks2) {
      int pc = ((ks2 * 4 + q4) ^ sx7) << 3;
      int ko = kt + ks2 * 32;
      short8 ah[4], al[4], bhf[4], blf[4];
#pragma unroll
      for (int mi = 0; mi < 4; ++mi) {
        int ra = (wr * 64 + mi * 16 + s) * 64 + pc;
        ah[mi] = *(const short8*)&Ah[ra];
        al[mi] = *(const short8*)&Al[ra];
      }
#pragma unroll
      for (int ni = 0; ni < 4; ++ni) {
        bhf[ni] = *(const short8*)(bHb + (size_t)ni * 16 * INNER + ko);
        blf[ni] = *(const short8*)(bLb + (size_t)ni * 16 * INNER + ko);
      }
#pragma unroll
      for (int mi = 0; mi < 4; ++mi)
#pragma unroll
        for (int ni = 0; ni < 4; ++ni) {
          acc[mi][ni] = __builtin_amdgcn_mfma_f32_16x16x32_bf16(al[mi], bhf[ni], acc[mi][ni], 0, 0, 0);
          acc[mi][ni] = __builtin_amdgcn_mfma_f32_16x16x32_bf16(ah[mi], blf[ni], acc[mi][ni], 0, 0, 0);
          acc[mi][ni] = __builtin_amdgcn_mfma_f32_16x16x32_bf16(ah[mi], bhf[ni], acc[mi][ni], 0, 0, 0);
        }
    }
  }

#pragma unroll
  for (int ni = 0; ni < 4; ++ni) {
    int Cl = c0 + wc * 64 + ni * 16 + s;
    float bv = bias[Cl];
#pragma unroll
    for (int mi = 0; mi < 4; ++mi)
#pragma unroll
      for (int i = 0; i < 4; ++i) {
        int R = r0 + wr * 64 + mi * 16 + q4 * 4 + i;
        C[(size_t)R * DIM + Cl] = acc[mi][ni][i] + bv;
      }
  }
}

extern "C" void kernel_launch(void* const* d_in, const int* in_sizes, int n_in,
                              void* d_out, int out_size, void* d_ws, size_t ws_size,
                              hipStream_t stream) {
  const float* x      = (const float*)d_in[0];
  const int*   cpmask = (const int*)d_in[1];
  const float* w_qkv  = (const float*)d_in[2];
  const float* w_out  = (const float*)d_in[3];
  const float* b_out  = (const float*)d_in[4];
  const int*   pic    = (const int*)d_in[5];
  float* out = (float*)d_out;

  unsigned short* xhi   = (unsigned short*)d_ws;       // 8192*512 (reused as ohi after qkv)
  unsigned short* xlo   = xhi + 4194304;               // (reused as olo)
  unsigned short* wqhiT = xlo + 4194304;               // 1536*512
  unsigned short* wqloT = wqhiT + 786432;
  unsigned short* wohiT = wqloT + 786432;              // 512*512
  unsigned short* woloT = wohiT + 262144;
  unsigned short* qhi   = woloT + 262144;              // 64*1024*64 each
  unsigned short* qlo   = qhi + 4194304;
  unsigned short* khi   = qlo + 4194304;
  unsigned short* klo   = khi + 4194304;
  unsigned short* vbp   = klo + 4194304;               // (unused; layout stability)
  float* sph  = (float*)(vbp + 4194304);               // 64*1024
  float* sc   = sph + 65536;                           // (unused slot)
  float* nnzf = sc + 8192;                             // 1024
  int*   asc  = (int*)(nnzf + 1024);                   // (unused slot)
  int*   src  = asc + 512;                             // 8192
  unsigned long long* Mbits = (unsigned long long*)(src + 8192);  // 16*1024
  unsigned short* vTp = (unsigned short*)(Mbits + 16384);         // 64*64*1024

  unsigned short* ohi = xhi;   // alias: x planes dead after qkv_mfma
  unsigned short* olo = xlo;

  hipLaunchKernelGGL(prep_kernel, dim3(5376),   dim3(256), 0, stream,
                     x, w_qkv, w_out, cpmask, xhi, xlo, wqhiT, wqloT, wohiT, woloT, nnzf, Mbits);
  hipLaunchKernelGGL(qkv_mfma,    dim3(768),    dim3(256), 0, stream, xhi, xlo, wqhiT, wqloT,
                     qhi, qlo, khi, klo, vTp);
  hipLaunchKernelGGL(attn_kernel, dim3(16, 64), dim3(256), 0, stream, qhi, qlo, khi, klo, vTp,
                     Mbits, ohi, olo, sph);
  hipLaunchKernelGGL(sel_build,   dim3(8),      dim3(64),  0, stream, sph, nnzf, pic, src);
  hipLaunchKernelGGL(out_mfma,    dim3(256),    dim3(256), 0, stream, ohi, olo, wohiT, woloT,
                     b_out, src, out);
}

// Round 9
// 226.295 us; speedup vs baseline: 1.0815x; 1.0815x over previous
//
#include <hip/hip_runtime.h>
#include <hip/hip_bf16.h>

#define NN 1024
#define DH 64
#define DIM 512
#define INNER 512
#define QKV_N 1536
#define SCALE 0.125f
#define PPITCH 72     // shorts; Ps plane (144B = 9*16B: b128-aligned)

typedef short short8 __attribute__((ext_vector_type(8)));
typedef float floatx4 __attribute__((ext_vector_type(4)));

static __device__ __forceinline__ unsigned short f2bf(float x) {
  __hip_bfloat16 h = __float2bfloat16(x);
  unsigned short u;
  __builtin_memcpy(&u, &h, 2);
  return u;
}
static __device__ __forceinline__ void splitbf(float x, unsigned short& hi, unsigned short& lo) {
  __hip_bfloat16 h = __float2bfloat16(x);
  float hf = __bfloat162float(h);
  __hip_bfloat16 l = __float2bfloat16(x - hf);
  __builtin_memcpy(&hi, &h, 2);
  __builtin_memcpy(&lo, &l, 2);
}
static __device__ __forceinline__ void gll16(const unsigned short* g, unsigned short* l) {
  __builtin_amdgcn_global_load_lds(
      (const __attribute__((address_space(1))) unsigned int*)g,
      (__attribute__((address_space(3))) unsigned int*)l, 16, 0, 0);
}

// ---------------- nnz + 64-col bitmasks per mask row (Mbits layout: [mt][row]) ----------------
__global__ __launch_bounds__(64) void nnz_kernel(const int* __restrict__ mask,
                                                 float* __restrict__ nnzf,
                                                 unsigned long long* __restrict__ Mbits) {
  int row = blockIdx.x;
  int lane = threadIdx.x;
  const int* mrow = mask + (size_t)row * NN;
  int tot = 0;
  for (int mt = 0; mt < 16; ++mt) {
    unsigned long long bits = __ballot(mrow[mt * 64 + lane] != 0);
    if (lane == 0) {
      Mbits[(size_t)mt * NN + row] = bits;
      tot += __popcll(bits);
    }
  }
  if (lane == 0) nnzf[row] = (float)tot;
}

// ---------------- split fp32 -> hi/lo bf16 ----------------
__global__ __launch_bounds__(256) void split_kernel(const float* __restrict__ in,
                                                    unsigned short* __restrict__ hi,
                                                    unsigned short* __restrict__ lo,
                                                    int n4) {
  int i = blockIdx.x * 256 + threadIdx.x;
  if (i >= n4) return;
  float4 v = ((const float4*)in)[i];
  ushort4 h, l;
  splitbf(v.x, h.x, l.x);
  splitbf(v.y, h.y, l.y);
  splitbf(v.z, h.z, l.z);
  splitbf(v.w, h.w, l.w);
  ((ushort4*)hi)[i] = h;
  ((ushort4*)lo)[i] = l;
}

// ---------------- transpose + split: in [K][N] fp32 -> hiT/loT [N][K] bf16 ----------------
__global__ __launch_bounds__(256) void tsplit_kernel(const float* __restrict__ in, int K, int N,
                                                     unsigned short* __restrict__ hiT,
                                                     unsigned short* __restrict__ loT) {
  __shared__ float tile[32][33];
  int n0 = blockIdx.x * 32, k0 = blockIdx.y * 32;
  int t = threadIdx.x;
  int tn = t & 31, tk = t >> 5;
#pragma unroll
  for (int i = 0; i < 32; i += 8)
    tile[tk + i][tn] = in[(size_t)(k0 + tk + i) * N + n0 + tn];
  __syncthreads();
#pragma unroll
  for (int i = 0; i < 32; i += 8) {
    int n = tk + i;
    float v = tile[tn][n];
    unsigned short h, l;
    splitbf(v, h, l);
    hiT[(size_t)(n0 + n) * K + k0 + tn] = h;
    loT[(size_t)(n0 + n) * K + k0 + tn] = l;
  }
}

// ---------------- QKV GEMM: BK=64, swizzled full-line gll16 staging, LDS-relayout epilogue ----------------
// grid 768 1-D: by = l&63 (row tile), bx = l>>6 (col tile). Same-A blocks share XCD (%8).
__global__ __launch_bounds__(256) void qkv_mfma(const unsigned short* __restrict__ xhi,
                                                const unsigned short* __restrict__ xlo,
                                                const unsigned short* __restrict__ bhiT,
                                                const unsigned short* __restrict__ bloT,
                                                unsigned short* __restrict__ qhi,
                                                unsigned short* __restrict__ qlo,
                                                unsigned short* __restrict__ khi,
                                                unsigned short* __restrict__ klo,
                                                unsigned short* __restrict__ vT) {
  // union: 4 bf16 planes [128][64] (65536 B)  |  fp32 C tile [128][132] (67584 B)
  __shared__ __align__(16) unsigned char smemQ[67584];
  unsigned short* planeS = (unsigned short*)smemQ;
  float* ct = (float*)smemQ;

  int l = blockIdx.x;
  int by = l & 63, bx = l >> 6;
  int r0 = by * 128, c0 = bx * 128;
  int which = c0 >> 9;                 // 0=q, 1=k, 2=v
  bool split3 = (which != 2);          // v: hi*hi only (rounded to bf16 anyway)
  int t = threadIdx.x;
  int lane = t & 63, w = t >> 6;
  int wr = w >> 1, wc = w & 1;
  int s = lane & 15, q4 = lane >> 4;
  int sx7 = s & 7;
  int r8 = lane >> 3, j7 = lane & 7;
  int colsw = ((j7 ^ r8) << 3);        // chunk swizzle keyed to LDS row&7 (= r8)

  // wave w stages plane w
  const unsigned short* gsrc;
  int tb;
  if (w == 0) { gsrc = xhi; tb = r0; }
  else if (w == 1) { gsrc = xlo; tb = r0; }
  else if (w == 2) { gsrc = bhiT; tb = c0; }
  else { gsrc = bloT; tb = c0; }
  unsigned short* lp = planeS + w * 8192;
  const unsigned short* gp = gsrc + (size_t)(tb + r8) * DIM + colsw;
  bool doStage = split3 || (w == 0) || (w == 2);

  const unsigned short* Ah = planeS;
  const unsigned short* Al = planeS + 8192;
  const unsigned short* Bh = planeS + 16384;
  const unsigned short* Bl = planeS + 24576;

  floatx4 acc[4][4];
#pragma unroll
  for (int mi = 0; mi < 4; ++mi)
#pragma unroll
    for (int ni = 0; ni < 4; ++ni) { acc[mi][ni][0] = 0.f; acc[mi][ni][1] = 0.f; acc[mi][ni][2] = 0.f; acc[mi][ni][3] = 0.f; }

  for (int kt = 0; kt < DIM; kt += 64) {
    __syncthreads();
    if (doStage) {
#pragma unroll
      for (int ii = 0; ii < 16; ++ii)
        gll16(gp + (size_t)ii * 8 * DIM + kt, lp + ii * 512);
    }
    __syncthreads();
#pragma unroll
    for (int ks2 = 0; ks2 < 2; ++ks2) {
      int pc = ((ks2 * 4 + q4) ^ sx7) << 3;
      short8 ah[4], al[4], bhf[4], blf[4];
#pragma unroll
      for (int mi = 0; mi < 4; ++mi) {
        int ra = (wr * 64 + mi * 16 + s) * 64 + pc;
        ah[mi] = *(const short8*)&Ah[ra];
        if (split3) al[mi] = *(const short8*)&Al[ra];
      }
#pragma unroll
      for (int ni = 0; ni < 4; ++ni) {
        int rb = (wc * 64 + ni * 16 + s) * 64 + pc;
        bhf[ni] = *(const short8*)&Bh[rb];
        if (split3) blf[ni] = *(const short8*)&Bl[rb];
      }
#pragma unroll
      for (int mi = 0; mi < 4; ++mi)
#pragma unroll
        for (int ni = 0; ni < 4; ++ni) {
          if (split3) {
            acc[mi][ni] = __builtin_amdgcn_mfma_f32_16x16x32_bf16(al[mi], bhf[ni], acc[mi][ni], 0, 0, 0);
            acc[mi][ni] = __builtin_amdgcn_mfma_f32_16x16x32_bf16(ah[mi], blf[ni], acc[mi][ni], 0, 0, 0);
          }
          acc[mi][ni] = __builtin_amdgcn_mfma_f32_16x16x32_bf16(ah[mi], bhf[ni], acc[mi][ni], 0, 0, 0);
        }
    }
  }

  // ---- epilogue: fp32 LDS relayout -> full-line split-bf16 stores ----
  __syncthreads();
  if (which != 2) {
    float sc = (which == 0) ? SCALE : 1.0f;
#pragma unroll
    for (int mi = 0; mi < 4; ++mi)
#pragma unroll
      for (int ni = 0; ni < 4; ++ni)
#pragma unroll
        for (int i = 0; i < 4; ++i)
          ct[(wr * 64 + mi * 16 + q4 * 4 + i) * 132 + (wc * 64 + ni * 16 + s)] = acc[mi][ni][i] * sc;
  } else {
#pragma unroll
    for (int mi = 0; mi < 4; ++mi)
#pragma unroll
      for (int ni = 0; ni < 4; ++ni)
#pragma unroll
        for (int i = 0; i < 4; ++i)
          ct[(wc * 64 + ni * 16 + s) * 132 + (wr * 64 + mi * 16 + q4 * 4 + i)] = acc[mi][ni][i];
  }
  __syncthreads();
  if (which != 2) {
    int tr = t >> 1, ch = t & 1;
    int R = r0 + tr, b = R >> 10, n = R & 1023;
    int h0 = ((c0 & 511) >> 6) + ch;
    unsigned short* dhi = (which == 0) ? qhi : khi;
    unsigned short* dlo = (which == 0) ? qlo : klo;
    size_t go = ((size_t)(((b << 3) + h0) << 10) + n) * DH;
#pragma unroll
    for (int u = 0; u < 4; ++u) {
      const float* src = &ct[tr * 132 + ch * 64 + u * 16];
      short8 h8a, h8b, l8a, l8b;
#pragma unroll
      for (int e = 0; e < 8; ++e) {
        unsigned short hh, ll;
        splitbf(src[e], hh, ll);
        h8a[e] = (short)hh; l8a[e] = (short)ll;
        splitbf(src[8 + e], hh, ll);
        h8b[e] = (short)hh; l8b[e] = (short)ll;
      }
      *(short8*)&dhi[go + u * 16] = h8a;
      *(short8*)&dhi[go + u * 16 + 8] = h8b;
      *(short8*)&dlo[go + u * 16] = l8a;
      *(short8*)&dlo[go + u * 16 + 8] = l8b;
    }
  } else {
    int cr = t >> 1, th = t & 1;
    int b = r0 >> 10;
    int hglob = ((c0 & 511) >> 6) + (cr >> 6);
    int d = cr & 63;
    int n0 = (r0 & 1023) + th * 64;
    size_t go = ((size_t)(((b << 3) + hglob) * DH) + d) * NN + n0;
#pragma unroll
    for (int u = 0; u < 4; ++u) {
      const float* src = &ct[cr * 132 + th * 64 + u * 16];
      short8 o0, o1;
#pragma unroll
      for (int e = 0; e < 8; ++e) {
        o0[e] = (short)f2bf(src[e]);
        o1[e] = (short)f2bf(src[8 + e]);
      }
      *(short8*)&vT[go + u * 16] = o0;
      *(short8*)&vT[go + u * 16 + 8] = o1;
    }
  }
}

// ---------------- MFMA flash attention: swizzled gll16 staging, LDS-relayout epilogue ----------------
__global__ __launch_bounds__(256, 4) void attn_kernel(const unsigned short* __restrict__ qhi,
                                                      const unsigned short* __restrict__ qlo,
                                                      const unsigned short* __restrict__ khi,
                                                      const unsigned short* __restrict__ klo,
                                                      const unsigned short* __restrict__ vT,
                                                      const unsigned long long* __restrict__ MbT,
                                                      unsigned short* __restrict__ ohi,
                                                      unsigned short* __restrict__ olo,
                                                      float* __restrict__ sph) {
  // XCD-affine swizzle: all 16 rb-blocks of one bh share (linear % 8)
  int l = blockIdx.y * 16 + blockIdx.x;
  int k = l >> 3;
  int rb = k & 15;
  int bh = (l & 7) + 8 * (k >> 4);
  int b = bh >> 3, h = bh & 7;
  int row0 = rb * 64;
  int t = threadIdx.x;
  int lane = t & 63, w = t >> 6;
  int q4 = lane >> 4, s = lane & 15;
  int sx7 = s & 7;
  int gr = 16 * w + s;
  int r8 = lane >> 3, j7 = lane & 7;
  int colsw = ((j7 ^ r8) << 3);

  __shared__ __align__(16) unsigned short stageS[3 * 4096];  // Khs | Kls | Vts, [64][64] each
  __shared__ __align__(16) unsigned short Ps[64 * PPITCH];
  __shared__ unsigned long long Mb[64];
  unsigned short* Khs = stageS;
  unsigned short* Kls = stageS + 4096;
  unsigned short* Vts = stageS + 8192;
  float* Ofl = (float*)stageS;   // [64][68] fp32, reused after main loop

  // staging source pointers (wave w stages rows 16w..16w+15 of each plane)
  const unsigned short* khp = khi + ((size_t)bh * NN + 16 * w + r8) * DH + colsw;
  const unsigned short* klp = klo + ((size_t)bh * NN + 16 * w + r8) * DH + colsw;
  const unsigned short* vtp = vT + ((size_t)bh * DH + 16 * w + r8) * NN + colsw;

  // Q fragments: direct global->register (pre-scaled, pre-split)
  short8 aqh[2], aql[2];
  {
    size_t qb0 = ((size_t)bh * NN + row0 + gr) * DH;
#pragma unroll
    for (int ks = 0; ks < 2; ++ks) {
      aqh[ks] = *(const short8*)&qhi[qb0 + ks * 32 + q4 * 8];
      aql[ks] = *(const short8*)&qlo[qb0 + ks * 32 + q4 * 8];
    }
  }

  floatx4 Oacc[4];
  float Lacc[4], Sco[4];
#pragma unroll
  for (int j = 0; j < 4; ++j) { Oacc[j][0] = 0.f; Oacc[j][1] = 0.f; Oacc[j][2] = 0.f; Oacc[j][3] = 0.f; }
#pragma unroll
  for (int i = 0; i < 4; ++i) { Lacc[i] = 0.f; Sco[i] = 0.f; }

  for (int mt = 0; mt < 16; ++mt) {
    __syncthreads();
#pragma unroll
    for (int ii = 0; ii < 2; ++ii) {
      int lofs = (16 * w + 8 * ii) * 64;
      gll16(khp + (size_t)mt * 64 * DH + (size_t)ii * 8 * DH, Khs + lofs);
      gll16(klp + (size_t)mt * 64 * DH + (size_t)ii * 8 * DH, Kls + lofs);
      gll16(vtp + (size_t)mt * 64 + (size_t)ii * 8 * NN, Vts + lofs);
    }
    if (t < 64) Mb[t] = MbT[(size_t)mt * NN + row0 + t];
    __syncthreads();

    // ---- S = Q K^T (3-MFMA split; logits pre-scaled) ----
    floatx4 Sf[4];
#pragma unroll
    for (int j = 0; j < 4; ++j) { Sf[j][0] = 0.f; Sf[j][1] = 0.f; Sf[j][2] = 0.f; Sf[j][3] = 0.f; }
#pragma unroll
    for (int ks = 0; ks < 2; ++ks) {
      int pc = ((ks * 4 + q4) ^ sx7) << 3;
#pragma unroll
      for (int j = 0; j < 4; ++j) {
        int rk = (16 * j + s) * 64 + pc;
        short8 kh8 = *(const short8*)&Khs[rk];
        short8 kl8 = *(const short8*)&Kls[rk];
        Sf[j] = __builtin_amdgcn_mfma_f32_16x16x32_bf16(aql[ks], kh8, Sf[j], 0, 0, 0);
        Sf[j] = __builtin_amdgcn_mfma_f32_16x16x32_bf16(aqh[ks], kl8, Sf[j], 0, 0, 0);
        Sf[j] = __builtin_amdgcn_mfma_f32_16x16x32_bf16(aqh[ks], kh8, Sf[j], 0, 0, 0);
      }
    }

    // ---- softmax weights + deferred per-lane L/S partials ----
    unsigned long long mb[4];
#pragma unroll
    for (int i = 0; i < 4; ++i) mb[i] = Mb[16 * w + 4 * q4 + i];
    unsigned short pw[4][4];
#pragma unroll
    for (int j = 0; j < 4; ++j) {
#pragma unroll
      for (int i = 0; i < 4; ++i) {
        float sv = Sf[j][i];
        float mf = ((mb[i] >> (16 * j + s)) & 1ULL) ? 1.0f : 0.0f;
        Sco[i] += fabsf(sv) * mf;
        float p = __expf(sv * mf);
        Lacc[i] += p;
        pw[i][j] = f2bf(p);
      }
    }

    // ---- P: C-layout -> A-layout via intra-wave LDS round-trip (no barrier) ----
#pragma unroll
    for (int i = 0; i < 4; ++i)
#pragma unroll
      for (int j = 0; j < 4; ++j) Ps[(16 * w + 4 * q4 + i) * PPITCH + 16 * j + s] = pw[i][j];

    // ---- O += P V ----
#pragma unroll
    for (int ks = 0; ks < 2; ++ks) {
      short8 ap = *(const short8*)&Ps[gr * PPITCH + ks * 32 + q4 * 8];
      int pc = ((ks * 4 + q4) ^ sx7) << 3;
#pragma unroll
      for (int j = 0; j < 4; ++j) {
        short8 bv = *(const short8*)&Vts[(16 * j + s) * 64 + pc];
        Oacc[j] = __builtin_amdgcn_mfma_f32_16x16x32_bf16(ap, bv, Oacc[j], 0, 0, 0);
      }
    }
  }

  // ---- final cross-lane reduction, sph ----
#pragma unroll
  for (int off = 1; off < 16; off <<= 1) {
#pragma unroll
    for (int i = 0; i < 4; ++i) {
      Lacc[i] += __shfl_xor(Lacc[i], off, 16);
      Sco[i] += __shfl_xor(Sco[i], off, 16);
    }
  }
  if (s == 0) {
#pragma unroll
    for (int i = 0; i < 4; ++i)
      sph[((size_t)bh << 10) + row0 + 16 * w + 4 * q4 + i] = Sco[i];
  }

  // ---- O epilogue: fp32 LDS relayout -> full-line split-bf16 stores ----
  __syncthreads();
#pragma unroll
  for (int i = 0; i < 4; ++i) {
    float iv = 1.0f / Lacc[i];
#pragma unroll
    for (int j = 0; j < 4; ++j)
      Ofl[(16 * w + 4 * q4 + i) * 68 + 16 * j + s] = Oacc[j][i] * iv;
  }
  __syncthreads();
  {
    int tr = t >> 2, dq = t & 3;
    int r = row0 + tr;
    size_t go = ((size_t)((b << 10) + r)) * INNER + (h << 6) + dq * 16;
    const float* src = &Ofl[tr * 68 + dq * 16];
    short8 h8a, h8b, l8a, l8b;
#pragma unroll
    for (int e = 0; e < 8; ++e) {
      unsigned short hh, ll;
      splitbf(src[e], hh, ll);
      h8a[e] = (short)hh; l8a[e] = (short)ll;
      splitbf(src[8 + e], hh, ll);
      h8b[e] = (short)hh; l8b[e] = (short)ll;
    }
    *(short8*)&ohi[go] = h8a;
    *(short8*)&ohi[go + 8] = h8b;
    *(short8*)&olo[go] = l8a;
    *(short8*)&olo[go + 8] = l8b;
  }
}

// ---------------- fused score + per-batch selection of (patches+1) smallest ----------------
__global__ __launch_bounds__(256) void score_select(const float* __restrict__ sph,
                                                    const float* __restrict__ nnzf,
                                                    const int* __restrict__ pic_ptr,
                                                    int* __restrict__ asc) {
  int bb = blockIdx.x;
  int t = threadIdx.x;
  int cnt = pic_ptr[0] + 1;
  float v[4];
#pragma unroll
  for (int i = 0; i < 4; ++i) {
    int r = t + 256 * i;
    float sv = 0.f;
#pragma unroll
    for (int h = 0; h < 8; ++h) sv += sph[(size_t)(((bb << 3) + h) << 10) + r];
    v[i] = sv / nnzf[r];
  }
  __shared__ float wv[4];
  __shared__ int wi[4];
  __shared__ int bsel;
  for (int sel = 0; sel < cnt; ++sel) {
    float bv = v[0];
    int bi = t;
#pragma unroll
    for (int i = 1; i < 4; ++i) {
      if (v[i] < bv) { bv = v[i]; bi = t + 256 * i; }
    }
#pragma unroll
    for (int off = 1; off < 64; off <<= 1) {
      float ov = __shfl_xor(bv, off, 64);
      int oi = __shfl_xor(bi, off, 64);
      if (ov < bv || (ov == bv && oi < bi)) { bv = ov; bi = oi; }
    }
    if ((t & 63) == 0) { wv[t >> 6] = bv; wi[t >> 6] = bi; }
    __syncthreads();
    if (t == 0) {
      float B = wv[0]; int I = wi[0];
#pragma unroll
      for (int q = 1; q < 4; ++q) {
        if (wv[q] < B || (wv[q] == B && wi[q] < I)) { B = wv[q]; I = wi[q]; }
      }
      bsel = I;
      asc[bb * 32 + sel] = I;
    }
    __syncthreads();
    int wloc = bsel - t;
    if (wloc >= 0 && (wloc & 255) == 0 && wloc < 1024) v[wloc >> 8] = 3.4e38f;
    __syncthreads();
  }
}

// ---------------- build row-gather map replicating the sequential swap loop ----------------
__global__ __launch_bounds__(256) void build_src(const int* __restrict__ asc,
                                                 const int* __restrict__ pic_ptr,
                                                 int* __restrict__ src) {
  int bi = blockIdx.x;
  int t = threadIdx.x;
  for (int r = t; r < 1024; r += 256) src[bi * 1024 + r] = r;
  __syncthreads();
  if (t == 0) {
    int pic = pic_ptr[0];
    const int* a = &asc[(7 - bi) * 32];   // [::-1] reverses the BATCH axis
    for (int i = 1; i <= pic; ++i) {
      int ti = a[i];
      src[bi * 1024 + i] = ti;
      src[bi * 1024 + ti] = i;
    }
  }
}

// ---------------- out GEMM: BK=64 swizzled gll16 staging, fused row gather + bias ----------------
// grid 256 1-D: by = l&63 (row tile), bx = l>>6 (col tile)
__global__ __launch_bounds__(256) void out_mfma(const unsigned short* __restrict__ ahi,
                                                const unsigned short* __restrict__ alo,
                                                const unsigned short* __restrict__ bhiT,
                                                const unsigned short* __restrict__ bloT,
                                                const float* __restrict__ bias,
                                                const int* __restrict__ src,
                                                float* __restrict__ C) {
  __shared__ __align__(16) unsigned short planeS[4 * 8192];
  int l = blockIdx.x;
  int by = l & 63, bx = l >> 6;
  int r0 = by * 128, c0 = bx * 128;
  int t = threadIdx.x;
  int lane = t & 63, w = t >> 6;
  int wr = w >> 1, wc = w & 1;
  int s = lane & 15, q4 = lane >> 4;
  int sx7 = s & 7;
  int r8 = lane >> 3, j7 = lane & 7;
  int colsw = ((j7 ^ r8) << 3);
  int bb1024 = (r0 >> 10) << 10;

  // per-lane gathered A rows (waves 0/1 only)
  int srcrow[16];
  if (w < 2) {
#pragma unroll
    for (int ii = 0; ii < 16; ++ii) srcrow[ii] = src[r0 + ii * 8 + r8];
  }
  const unsigned short* gsrc = (w == 0) ? ahi : (w == 1) ? alo : (w == 2) ? bhiT : bloT;
  unsigned short* lp = planeS + w * 8192;

  const unsigned short* Ah = planeS;
  const unsigned short* Al = planeS + 8192;
  const unsigned short* Bh = planeS + 16384;
  const unsigned short* Bl = planeS + 24576;

  floatx4 acc[4][4];
#pragma unroll
  for (int mi = 0; mi < 4; ++mi)
#pragma unroll
    for (int ni = 0; ni < 4; ++ni) { acc[mi][ni][0] = 0.f; acc[mi][ni][1] = 0.f; acc[mi][ni][2] = 0.f; acc[mi][ni][3] = 0.f; }

  for (int kt = 0; kt < INNER; kt += 64) {
    __syncthreads();
    if (w < 2) {
#pragma unroll
      for (int ii = 0; ii < 16; ++ii)
        gll16(gsrc + (size_t)(bb1024 + srcrow[ii]) * INNER + kt + colsw, lp + ii * 512);
    } else {
#pragma unroll
      for (int ii = 0; ii < 16; ++ii)
        gll16(gsrc + (size_t)(c0 + ii * 8 + r8) * INNER + kt + colsw, lp + ii * 512);
    }
    __syncthreads();
#pragma unroll
    for (int ks2 = 0; ks2 < 2; ++ks2) {
      int pc = ((ks2 * 4 + q4) ^ sx7) << 3;
      short8 ah[4], al[4], bhf[4], blf[4];
#pragma unroll
      for (int mi = 0; mi < 4; ++mi) {
        int ra = (wr * 64 + mi * 16 + s) * 64 + pc;
        ah[mi] = *(const short8*)&Ah[ra];
        al[mi] = *(const short8*)&Al[ra];
      }
#pragma unroll
      for (int ni = 0; ni < 4; ++ni) {
        int rb = (wc * 64 + ni * 16 + s) * 64 + pc;
        bhf[ni] = *(const short8*)&Bh[rb];
        blf[ni] = *(const short8*)&Bl[rb];
      }
#pragma unroll
      for (int mi = 0; mi < 4; ++mi)
#pragma unroll
        for (int ni = 0; ni < 4; ++ni) {
          acc[mi][ni] = __builtin_amdgcn_mfma_f32_16x16x32_bf16(al[mi], bhf[ni], acc[mi][ni], 0, 0, 0);
          acc[mi][ni] = __builtin_amdgcn_mfma_f32_16x16x32_bf16(ah[mi], blf[ni], acc[mi][ni], 0, 0, 0);
          acc[mi][ni] = __builtin_amdgcn_mfma_f32_16x16x32_bf16(ah[mi], bhf[ni], acc[mi][ni], 0, 0, 0);
        }
    }
  }

#pragma unroll
  for (int ni = 0; ni < 4; ++ni) {
    int Cl = c0 + wc * 64 + ni * 16 + s;
    float bv = bias[Cl];
#pragma unroll
    for (int mi = 0; mi < 4; ++mi)
#pragma unroll
      for (int i = 0; i < 4; ++i) {
        int R = r0 + wr * 64 + mi * 16 + q4 * 4 + i;
        C[(size_t)R * DIM + Cl] = acc[mi][ni][i] + bv;
      }
  }
}

extern "C" void kernel_launch(void* const* d_in, const int* in_sizes, int n_in,
                              void* d_out, int out_size, void* d_ws, size_t ws_size,
                              hipStream_t stream) {
  const float* x      = (const float*)d_in[0];
  const int*   cpmask = (const int*)d_in[1];
  const float* w_qkv  = (const float*)d_in[2];
  const float* w_out  = (const float*)d_in[3];
  const float* b_out  = (const float*)d_in[4];
  const int*   pic    = (const int*)d_in[5];
  float* out = (float*)d_out;

  unsigned short* xhi   = (unsigned short*)d_ws;       // 8192*512 (reused as ohi after qkv)
  unsigned short* xlo   = xhi + 4194304;               // (reused as olo)
  unsigned short* wqhiT = xlo + 4194304;               // 1536*512
  unsigned short* wqloT = wqhiT + 786432;
  unsigned short* wohiT = wqloT + 786432;              // 512*512
  unsigned short* woloT = wohiT + 262144;
  unsigned short* qhi   = woloT + 262144;              // 64*1024*64 each
  unsigned short* qlo   = qhi + 4194304;
  unsigned short* khi   = qlo + 4194304;
  unsigned short* klo   = khi + 4194304;
  unsigned short* vbp   = klo + 4194304;               // (unused; layout stability)
  float* sph  = (float*)(vbp + 4194304);               // 64*1024
  float* sc   = sph + 65536;                           // (unused slot)
  float* nnzf = sc + 8192;                             // 1024
  int*   asc  = (int*)(nnzf + 1024);                   // 8*32
  int*   src  = asc + 512;                             // 8192
  unsigned long long* Mbits = (unsigned long long*)(src + 8192);  // 16*1024
  unsigned short* vTp = (unsigned short*)(Mbits + 16384);         // 64*64*1024

  unsigned short* ohi = xhi;   // alias: x planes dead after qkv_mfma
  unsigned short* olo = xlo;

  hipLaunchKernelGGL(nnz_kernel,    dim3(1024),    dim3(64),  0, stream, cpmask, nnzf, Mbits);
  hipLaunchKernelGGL(split_kernel,  dim3(4096),    dim3(256), 0, stream, x, xhi, xlo, 1048576);
  hipLaunchKernelGGL(tsplit_kernel, dim3(48, 16),  dim3(256), 0, stream, w_qkv, DIM, QKV_N, wqhiT, wqloT);
  hipLaunchKernelGGL(tsplit_kernel, dim3(16, 16),  dim3(256), 0, stream, w_out, INNER, DIM, wohiT, woloT);
  hipLaunchKernelGGL(qkv_mfma,      dim3(768),     dim3(256), 0, stream, xhi, xlo, wqhiT, wqloT,
                     qhi, qlo, khi, klo, vTp);
  hipLaunchKernelGGL(attn_kernel,   dim3(16, 64),  dim3(256), 0, stream, qhi, qlo, khi, klo, vTp,
                     Mbits, ohi, olo, sph);
  hipLaunchKernelGGL(score_select,  dim3(8),       dim3(256), 0, stream, sph, nnzf, pic, asc);
  hipLaunchKernelGGL(build_src,     dim3(8),       dim3(256), 0, stream, asc, pic, src);
  hipLaunchKernelGGL(out_mfma,      dim3(256),     dim3(256), 0, stream, ohi, olo, wohiT, woloT,
                     b_out, src, out);
}